// Round 2
// baseline (439.471 us; speedup 1.0000x reference)
//
#include <hip/hip_runtime.h>

#define NLVL 16
#define NTOT 1846083
#define NBLK 2254

typedef float  f32x4  __attribute__((ext_vector_type(4)));
typedef __bf16 bf16x8 __attribute__((ext_vector_type(8)));
typedef unsigned int u32;
typedef unsigned int u32x4 __attribute__((ext_vector_type(4)));

// level tables (static in reference)
__constant__ int c_R[NLVL]   = {16,18,20,22,25,27,30,34,38,42,47,52,58,64,72,80};
__constant__ int c_off[NLVL] = {0,4096,9928,17928,28576,44201,63884,90884,130188,185060,259148,362971,503579,698691,960835,1334083};
__constant__ int c_czy[NLVL] = {2,3,3,3,4,4,4,5,5,6,6,7,8,8,9,10};          // ceil(R/8)  (8-row y-tiles)
__constant__ int c_cx[NLVL]  = {1,2,2,2,2,2,2,3,3,3,3,4,4,4,5,5};           // ceil(R/16) (x-tiles = z-chunks)
// blocks ordered level 15 -> 0 (longest first); count[l] = 2*czy*cx*cx
__constant__ int c_base[17]  = {0,500,950,1206,1462,1686,1794,1902,1992,2082,2114,2146,2178,2202,2226,2250,2254};

// B fragments: [level][kz(3)][pair(5)][lane(64)][8 bf16] = 240 KB
__device__ __align__(16) unsigned short g_bfrag[NLVL*3*5*64*8];
// 16B zero source for halo/OOB lanes of global_load_lds
__device__ __align__(16) float g_zero[4] = {0.f, 0.f, 0.f, 0.f};

// ---------------------------------------------------------------------------
// Pack weights into MFMA A-operand fragments (weights-as-A, data-as-B).
// A[m=co][k]: m=lane&15, k=(lane>>4)*8+j; k -> tip=k>>4, ci=k&15;
// in-plane tap t2 = 2*pair + tip (t2==9 padded with zero weight).
// ---------------------------------------------------------------------------
__global__ void prep_bfrag(const float* __restrict__ wgt) {
    int tid = blockIdx.x * 256 + threadIdx.x;
    if (tid >= NLVL*3*5*64) return;
    int lane = tid & 63;
    int p    = (tid >> 6) % 5;
    int d    = (tid / (5*64)) % 3;
    int l    = tid / (3*5*64);
    int quad = lane >> 4, co = lane & 15;
    unsigned short v[8];
#pragma unroll
    for (int j = 0; j < 8; ++j) {
        int k   = quad*8 + j;
        int tip = k >> 4;
        int ci  = k & 15;
        int t2  = 2*p + tip;
        float f = (t2 < 9) ? wgt[((l*27 + d*9 + t2)*16 + ci)*16 + co] : 0.f;
        v[j] = __builtin_bit_cast(unsigned short, (__bf16)f);
    }
    u32x4 pk;
    pk[0] = (u32)v[0] | ((u32)v[1] << 16);
    pk[1] = (u32)v[2] | ((u32)v[3] << 16);
    pk[2] = (u32)v[4] | ((u32)v[5] << 16);
    pk[3] = (u32)v[6] | ((u32)v[7] << 16);
    *(u32x4*)&g_bfrag[(size_t)tid*8] = pk;
}

__device__ __forceinline__ void gll16(const void* g, void* l) {
    __builtin_amdgcn_global_load_lds(
        (const __attribute__((address_space(1))) u32*)g,
        (__attribute__((address_space(3))) u32*)l, 16, 0, 0);
}

// ---------------------------------------------------------------------------
// Streaming-z conv: block = 4 waves, tile 16x * 8y (2 rows/wave), z-chunk 16.
// f32 planes staged directly to LDS via global_load_lds (zero-source redirect
// for halo), 3-plane ring + counted vmcnt(3) -> 2-step prefetch window.
// Per step: 20 ds_read_b128 -> 10 bf16 A-frags -> 30 MFMA into rolling accs.
// Stores issued at step START (oldest in vmcnt FIFO, never waited on).
// ---------------------------------------------------------------------------
__global__ __launch_bounds__(256, 4)
void conv_kernel(const float* __restrict__ in,
                 const float* __restrict__ bias,
                 float* __restrict__ out) {
    // plane: [yp 0..9][xp 0..17][ci 0..15] f32 = 11520 B; ring of 3
    __shared__ __align__(16) float slab[3*2880];

    const int bid = blockIdx.x;
    int idx = 0;
#pragma unroll
    for (int i = 1; i < 16; ++i) if (bid >= c_base[i]) idx = i;
    const int l = 15 - idx;
    const int R = c_R[l], off = c_off[l], czy = c_czy[l], cx = c_cx[l];

    int local = bid - c_base[idx];
    int per_b = czy*cx*cx;
    int bb = local / per_b;         int r1 = local - bb*per_b;
    int zt = r1 / (czy*cx);         int r2 = r1 - zt*(czy*cx);
    int yt = r2 / cx;               int xt = r2 - yt*cx;
    const int z0 = zt*16;
    const int z1 = (z0 + 16 < R) ? z0 + 16 : R;
    const int y0 = yt*8, x0 = xt*16;

    // ---- per-lane constants ----
    const int t    = threadIdx.x;
    const int lane = t & 63;
    const int wv   = t >> 6;
    const int quad = lane >> 4;
    const int m    = lane & 15;
    const int qh   = quad >> 1;

    // ---- weight fragments resident (15 x 16B per lane) ----
    bf16x8 bfr[15];
#pragma unroll
    for (int d = 0; d < 3; ++d)
#pragma unroll
        for (int p = 0; p < 5; ++p)
            bfr[d*5+p] = *(const bf16x8*)&g_bfrag[(size_t)(((l*3 + d)*5 + p)*64 + lane)*8];

    // ---- A-frag byte offsets within an f32 plane (5 pairs, row r0) ----
    // row stride 1152B; toff(t2) = (t2/3)*1152 + (t2%3)*64; qh picks tap in pair
    const int albase = wv*2304 + m*64 + (quad & 1)*32;
    int aoff[5];
    {
        const int T0[5] = {0, 128, 1216, 2304, 2432};
        const int T1[5] = {64, 1152, 1280, 2368, 2432};
#pragma unroll
        for (int p = 0; p < 5; ++p) aoff[p] = albase + (qh ? T1[p] : T0[p]);
    }

    // ---- staging precompute: plane = 720 chunks of 16B; slots c=t, t+256, t+512 ----
    const long zs = (long)R*R*16;          // f32 elements per plane
    const long gstart = ((long)bb*NTOT + off)*16;
    const float* cur[3]; bool ok[3];
    {
#pragma unroll
        for (int s = 0; s < 3; ++s) {
            int c = t + s*256;
            int yp = c/72; int rem = c - yp*72; int xp = rem>>2; int ci4 = (rem&3)<<2;
            int y = y0 + yp - 1, x = x0 + xp - 1;
            ok[s] = ((unsigned)y < (unsigned)R) && ((unsigned)x < (unsigned)R);
            cur[s] = in + gstart + ((long)y*R + x)*16 + ci4 + (long)(z0-1)*zs;
        }
    }
    const bool has2 = (t < 208);           // slot 2 valid chunks: c < 720

    float* b0 = slab;            // ring buffers
    float* b1 = slab + 2880;
    float* b2 = slab + 5760;

    const float* zv = g_zero;
    char* const lw = (char*)0 + wv*1024;   // per-wave LDS byte offset (as int)
    const int wvo = wv*1024;

    // ---- prologue: issue plane z0-1 -> b0, plane z0 -> b1 ----
    {
        bool zrA = (z0 - 1) >= 0;
        gll16(zrA && ok[0] ? cur[0] : zv, (char*)b0 + wvo);
        gll16(zrA && ok[1] ? cur[1] : zv, (char*)b0 + wvo + 4096);
        if (has2) gll16(zrA && ok[2] ? cur[2] : zv, (char*)b0 + wvo + 8192);
        gll16(ok[0] ? cur[0] + zs : zv, (char*)b1 + wvo);
        gll16(ok[1] ? cur[1] + zs : zv, (char*)b1 + wvo + 4096);
        if (has2) gll16(ok[2] ? cur[2] + zs : zv, (char*)b1 + wvo + 8192);
        cur[0] += 2*zs; cur[1] += 2*zs; cur[2] += 2*zs;
    }
    asm volatile("s_waitcnt vmcnt(3)" ::: "memory");
    __builtin_amdgcn_s_barrier();
    asm volatile("" ::: "memory");

    const int yo0 = y0 + 2*wv, yo1 = yo0 + 1;
    const bool yw0 = yo0 < R, yw1 = yo1 < R;
    const bool xok = (x0 + m) < R;
    const f32x4 bv4 = *(const f32x4*)(bias + (l << 4) + (quad << 2));

    // running store pointers (plane z0, rows yo0/yo1)
    float* so0 = out + gstart + (((long)z0*R + yo0)*(long)R + x0 + m)*16 + (quad << 2);
    float* so1 = so0 + (long)R*16;

    const f32x4 zero4 = {0,0,0,0};
    f32x4 aA0 = zero4, aB0 = zero4, aC0 = zero4;
    f32x4 aA1 = zero4, aB1 = zero4, aC1 = zero4;
    f32x4 aO0 = zero4, aO1 = zero4;

    const int steps = z1 - z0 + 2;

#pragma unroll 1
    for (int i = 0; i < steps; ++i) {
        // 1) store plane z0+i-3 (completed at end of step i-1), oldest in vmcnt FIFO
        if (i >= 3) {
            if (yw0) { f32x4 o = aO0 + bv4; if (xok) *(f32x4*)so0 = o; }
            if (yw1) { f32x4 o = aO1 + bv4; if (xok) *(f32x4*)so1 = o; }
            so0 += zs; so1 += zs;
        }

        // 2) issue staging for plane zn = z0+1+i into b2 (always 3 issues/wave)
        {
            const int zn = z0 + 1 + i;
            const bool zr = (zn <= z1) && (zn < R);
            gll16(zr && ok[0] ? cur[0] : zv, (char*)b2 + wvo);
            gll16(zr && ok[1] ? cur[1] : zv, (char*)b2 + wvo + 4096);
            if (has2) gll16(zr && ok[2] ? cur[2] : zv, (char*)b2 + wvo + 8192);
            cur[0] += zs; cur[1] += zs; cur[2] += zs;
        }

        // 3) compute plane zp = z0-1+i from b0
        const char* sb = (const char*)b0;
#pragma unroll
        for (int p = 0; p < 5; ++p) {
            const char* sa = sb + aoff[p];
            f32x4 q00 = *(const f32x4*)(sa);
            f32x4 q01 = *(const f32x4*)(sa + 16);
            f32x4 q10 = *(const f32x4*)(sa + 1152);
            f32x4 q11 = *(const f32x4*)(sa + 1168);
            bf16x8 A0 = {(__bf16)q00[0],(__bf16)q00[1],(__bf16)q00[2],(__bf16)q00[3],
                         (__bf16)q01[0],(__bf16)q01[1],(__bf16)q01[2],(__bf16)q01[3]};
            bf16x8 A1 = {(__bf16)q10[0],(__bf16)q10[1],(__bf16)q10[2],(__bf16)q10[3],
                         (__bf16)q11[0],(__bf16)q11[1],(__bf16)q11[2],(__bf16)q11[3]};
            aC0 = __builtin_amdgcn_mfma_f32_16x16x32_bf16(bfr[p],    A0, aC0, 0, 0, 0); // kz=0 -> out zp+1
            aC1 = __builtin_amdgcn_mfma_f32_16x16x32_bf16(bfr[p],    A1, aC1, 0, 0, 0);
            aB0 = __builtin_amdgcn_mfma_f32_16x16x32_bf16(bfr[5+p],  A0, aB0, 0, 0, 0); // kz=1 -> out zp
            aB1 = __builtin_amdgcn_mfma_f32_16x16x32_bf16(bfr[5+p],  A1, aB1, 0, 0, 0);
            aA0 = __builtin_amdgcn_mfma_f32_16x16x32_bf16(bfr[10+p], A0, aA0, 0, 0, 0); // kz=2 -> out zp-1
            aA1 = __builtin_amdgcn_mfma_f32_16x16x32_bf16(bfr[10+p], A1, aA1, 0, 0, 0);
        }

        // 4) rotate accumulators; drain plane needed next step (prev step's 3
        //    issues); this step's 3 issues stay in flight across the barrier
        aO0 = aA0; aA0 = aB0; aB0 = aC0; aC0 = zero4;
        aO1 = aA1; aA1 = aB1; aB1 = aC1; aC1 = zero4;

        asm volatile("s_waitcnt vmcnt(3)" ::: "memory");
        __builtin_amdgcn_s_barrier();
        asm volatile("" ::: "memory");

        float* tmp = b0; b0 = b1; b1 = b2; b2 = tmp;
    }

    // epilogue: store plane z1-1
    if (yw0) { f32x4 o = aO0 + bv4; if (xok) *(f32x4*)so0 = o; }
    if (yw1) { f32x4 o = aO1 + bv4; if (xok) *(f32x4*)so1 = o; }
}

extern "C" void kernel_launch(void* const* d_in, const int* in_sizes, int n_in,
                              void* d_out, int out_size, void* d_ws, size_t ws_size,
                              hipStream_t stream) {
    const float* inp = (const float*)d_in[0];
    const float* wgt = (const float*)d_in[1];
    const float* bia = (const float*)d_in[2];
    float* out = (float*)d_out;
    prep_bfrag<<<dim3((NLVL*3*5*64 + 255)/256), dim3(256), 0, stream>>>(wgt);
    conv_kernel<<<dim3(NBLK), dim3(256), 0, stream>>>(inp, bia, out);
}

// Round 3
// 426.116 us; speedup vs baseline: 1.0313x; 1.0313x over previous
//
#include <hip/hip_runtime.h>

#define NLVL 16
#define NTOT 1846083
#define NTILE 4376
#define NBLOCK 1094   // 4 wave-tiles per block

typedef float  f32x4  __attribute__((ext_vector_type(4)));
typedef __bf16 bf16x8 __attribute__((ext_vector_type(8)));
typedef __bf16 bf16x4 __attribute__((ext_vector_type(4)));
typedef unsigned int u32;
typedef unsigned int u32x4 __attribute__((ext_vector_type(4)));

// level tables (static in reference)
__constant__ int c_R[NLVL]   = {16,18,20,22,25,27,30,34,38,42,47,52,58,64,72,80};
__constant__ int c_off[NLVL] = {0,4096,9928,17928,28576,44201,63884,90884,130188,185060,259148,362971,503579,698691,960835,1334083};
__constant__ int c_czy[NLVL] = {4,5,5,6,7,7,8,9,10,11,12,13,15,16,18,20};   // ceil(R/4)  (4-row wave tiles)
__constant__ int c_cx[NLVL]  = {1,2,2,2,2,2,2,3,3,3,3,4,4,4,5,5};           // ceil(R/16) (x-tiles = z-chunks)
// wave-tiles ordered level 15 -> 0 (longest first); count[l] = 2*czy*cx*cx
__constant__ int c_base[17]  = {0,1000,1900,2412,2892,3308,3524,3722,3902,4064,4128,4184,4240,4288,4328,4368,4376};

// weight fragments: [level][kz(3)][pair(5)][lane(64)][8 bf16] = 240 KB
__device__ __align__(16) unsigned short g_bfrag[NLVL*3*5*64*8];

// ---------------------------------------------------------------------------
// Pack weights into MFMA A-operand fragments (weights-as-A, data-as-B).
// A[m=co][k]: m=lane&15, k=(lane>>4)*8+j; k -> tip=k>>4, ci=k&15;
// in-plane tap t2 = 2*pair + tip (t2==9 padded with zero weight).
// ---------------------------------------------------------------------------
__global__ void prep_bfrag(const float* __restrict__ wgt) {
    int tid = blockIdx.x * 256 + threadIdx.x;
    if (tid >= NLVL*3*5*64) return;
    int lane = tid & 63;
    int p    = (tid >> 6) % 5;
    int d    = (tid / (5*64)) % 3;
    int l    = tid / (3*5*64);
    int quad = lane >> 4, co = lane & 15;
    unsigned short v[8];
#pragma unroll
    for (int j = 0; j < 8; ++j) {
        int k   = quad*8 + j;
        int tip = k >> 4;
        int ci  = k & 15;
        int t2  = 2*p + tip;
        float f = (t2 < 9) ? wgt[((l*27 + d*9 + t2)*16 + ci)*16 + co] : 0.f;
        v[j] = __builtin_bit_cast(unsigned short, (__bf16)f);
    }
    u32x4 pk;
    pk[0] = (u32)v[0] | ((u32)v[1] << 16);
    pk[1] = (u32)v[2] | ((u32)v[3] << 16);
    pk[2] = (u32)v[4] | ((u32)v[5] << 16);
    pk[3] = (u32)v[6] | ((u32)v[7] << 16);
    *(u32x4*)&g_bfrag[(size_t)tid*8] = pk;
}

// ---------------------------------------------------------------------------
// Barrier-free streaming-z conv. Each WAVE owns a 16x * 4y tile and streams a
// 16-deep z-chunk independently: global->reg (2-set ping-pong) -> cvt -> bf16
// LDS plane (own 8KB region, 2-plane ping-pong) -> 20 ds_read_b128 -> 60 MFMA
// into 3 statically-rotated acc slots (6-body unroll: mod-3 slot x mod-2 buf).
// All sync is intra-wave: compiler emits precise counted waitcnt, no barriers.
// ---------------------------------------------------------------------------
__global__ __launch_bounds__(256, 2)
void conv_kernel(const float* __restrict__ in,
                 const float* __restrict__ bias,
                 float* __restrict__ out) {
    // per-wave 8KB region: two bf16 planes [yp 0..5][xp 0..17][ci 0..15] at +0/+4096
    __shared__ __align__(16) char slab[4*8192];

    const int t    = threadIdx.x;
    const int lane = t & 63;
    const int wv   = t >> 6;

    const int tid4 = blockIdx.x*4 + wv;
    int idx = 0;
#pragma unroll
    for (int i = 1; i < 16; ++i) if (tid4 >= c_base[i]) idx = i;
    const int l = 15 - idx;
    const int R = c_R[l], off = c_off[l], czy = c_czy[l], cx = c_cx[l];

    int local = tid4 - c_base[idx];
    int per_b = czy*cx*cx;
    int bb = local / per_b;         int r1 = local - bb*per_b;
    int zt = r1 / (czy*cx);         int r2 = r1 - zt*(czy*cx);
    int yt = r2 / cx;               int xt = r2 - yt*cx;
    const int z0 = zt*16;
    const int z1 = (z0 + 16 < R) ? z0 + 16 : R;
    const int y0 = yt*4, x0 = xt*16;
    const int steps = z1 - z0 + 2;

    const int quad = lane >> 4;
    const int m    = lane & 15;
    const int qh   = quad >> 1;

    // ---- weight fragments resident (15 x 16B per lane) ----
    bf16x8 bfr[15];
#pragma unroll
    for (int d = 0; d < 3; ++d)
#pragma unroll
        for (int p = 0; p < 5; ++p)
            bfr[d*5+p] = *(const bf16x8*)&g_bfrag[(size_t)(((l*3 + d)*5 + p)*64 + lane)*8];

    // ---- A-frag LDS base pointers (5 pairs; +PAR*4096 +r*576 folded as imm) ----
    const char* sbase = (const char*)slab + wv*8192;
    const char* arA[5];
    {
        const int T0[5] = {0, 64, 608, 1152, 1216};
        const int T1[5] = {32, 576, 640, 1184, 1216};
        const int ab = m*32 + (quad & 1)*16;
#pragma unroll
        for (int p = 0; p < 5; ++p) arA[p] = sbase + ab + (qh ? T1[p] : T0[p]);
    }
    char* wbase = (char*)slab + wv*8192 + lane*8;

    // ---- staging: plane = 432 f32x4 chunks; slot s covers chunk lane+s*64 ----
    const int  zsE = R*R*16;            // f32 elements per z-plane
    const u32  zsB = (u32)zsE*4;        // bytes per z-plane
    const long gstartE = ((long)bb*NTOT + off)*16;

    u32 cur[7]; bool okk[7];
#pragma unroll
    for (int s = 0; s < 7; ++s) {
        int c = lane + s*64;
        int yp = c/72; int rem = c - yp*72; int xp = rem>>2; int ci4 = (rem&3)<<2;
        int y = y0 + yp - 1, x = x0 + xp - 1;
        okk[s] = (c < 432) && ((unsigned)y < (unsigned)R) && ((unsigned)x < (unsigned)R);
        long e = gstartE + (long)(z0-1)*zsE + ((long)y*R + x)*16 + ci4;
        cur[s] = (u32)(e*4);            // byte offset; only deref'd when guarded valid
    }

    const f32x4 z4 = {0,0,0,0};
    f32x4 LA[7], LB[7];

    // ---- prologue: plane z0-1 -> LA -> buf0; plane z0 -> LB (held in regs) ----
    {
        const bool zrA = (z0 > 0);
#pragma unroll
        for (int s = 0; s < 7; ++s) { f32x4 v = z4; if (zrA && okk[s]) v = *(const f32x4*)((const char*)in + cur[s]); LA[s] = v; }
#pragma unroll
        for (int s = 0; s < 7; ++s) cur[s] += zsB;
#pragma unroll
        for (int s = 0; s < 7; ++s) { f32x4 v = z4; if (okk[s]) v = *(const f32x4*)((const char*)in + cur[s]); LB[s] = v; }
#pragma unroll
        for (int s = 0; s < 7; ++s) cur[s] += zsB;
#pragma unroll
        for (int s = 0; s < 7; ++s) {
            bf16x4 h = {(__bf16)LA[s][0],(__bf16)LA[s][1],(__bf16)LA[s][2],(__bf16)LA[s][3]};
            *(bf16x4*)(wbase + s*512) = h;
        }
    }

    const bool xok = (x0 + m) < R;
    bool ywr[4];
#pragma unroll
    for (int r = 0; r < 4; ++r) ywr[r] = (y0 + r) < R;
    const f32x4 bv4 = *(const f32x4*)(bias + (l << 4) + (quad << 2));

    float* so[4];
#pragma unroll
    for (int r = 0; r < 4; ++r)
        so[r] = out + gstartE + (((long)z0*R + (y0 + r))*(long)R + (x0 + m))*16 + (quad << 2);

    f32x4 acc0[4], acc1[4], acc2[4];
#pragma unroll
    for (int r = 0; r < 4; ++r) { acc0[r] = z4; acc1[r] = z4; acc2[r] = z4; }

    int zl = z0 + 1;   // plane loaded by the next body

    // Body II: loads plane zl into LN; computes plane z0-1+II from buf(PAR);
    // cvt-writes LO (plane z0+II) into buf(PAR^1); AZ completes out plane II-2.
#define BODY(II, PAR, LN, LO, AX, AY, AZ, ENST)                                         \
    {                                                                                   \
        const bool zr = (zl <= z1) && (zl < R);                                         \
        _Pragma("unroll")                                                               \
        for (int s = 0; s < 7; ++s) {                                                   \
            f32x4 v = z4;                                                               \
            if (zr && okk[s]) v = *(const f32x4*)((const char*)in + cur[s]);            \
            LN[s] = v;                                                                  \
        }                                                                               \
        { u32 a_ = zr ? zsB : 0u;                                                       \
          _Pragma("unroll") for (int s = 0; s < 7; ++s) cur[s] += a_; }                 \
        ++zl;                                                                           \
        _Pragma("unroll")                                                               \
        for (int p = 0; p < 5; ++p) {                                                   \
            _Pragma("unroll")                                                           \
            for (int r = 0; r < 4; ++r) {                                               \
                bf16x8 af = *(const bf16x8*)(arA[p] + (PAR)*4096 + r*576);              \
                AX[r] = __builtin_amdgcn_mfma_f32_16x16x32_bf16(bfr[p],    af, AX[r], 0,0,0); \
                AY[r] = __builtin_amdgcn_mfma_f32_16x16x32_bf16(bfr[5+p],  af, AY[r], 0,0,0); \
                AZ[r] = __builtin_amdgcn_mfma_f32_16x16x32_bf16(bfr[10+p], af, AZ[r], 0,0,0); \
            }                                                                           \
        }                                                                               \
        _Pragma("unroll")                                                               \
        for (int s = 0; s < 7; ++s) {                                                   \
            bf16x4 h = {(__bf16)LO[s][0],(__bf16)LO[s][1],(__bf16)LO[s][2],(__bf16)LO[s][3]}; \
            *(bf16x4*)(wbase + ((PAR)^1)*4096 + s*512) = h;                             \
        }                                                                               \
        if ((ENST) && (II) < steps) {                                                   \
            _Pragma("unroll")                                                           \
            for (int r = 0; r < 4; ++r) {                                               \
                if (ywr[r] && xok) { f32x4 o_ = AZ[r] + bv4; *(f32x4*)so[r] = o_; }     \
                so[r] += zsE;                                                           \
            }                                                                           \
        }                                                                               \
        _Pragma("unroll")                                                               \
        for (int r = 0; r < 4; ++r) AZ[r] = z4;                                         \
    }

    BODY(0, 0, LA, LB, acc0, acc2, acc1, 0)
    BODY(1, 1, LB, LA, acc1, acc0, acc2, 0)
    BODY(2, 0, LA, LB, acc2, acc1, acc0, 1)
    BODY(3, 1, LB, LA, acc0, acc2, acc1, 1)
    BODY(4, 0, LA, LB, acc1, acc0, acc2, 1)
    BODY(5, 1, LB, LA, acc2, acc1, acc0, 1)
#pragma unroll 1
    for (int i = 6; i < steps; i += 6) {
        BODY(i+0, 0, LA, LB, acc0, acc2, acc1, 1)
        BODY(i+1, 1, LB, LA, acc1, acc0, acc2, 1)
        BODY(i+2, 0, LA, LB, acc2, acc1, acc0, 1)
        BODY(i+3, 1, LB, LA, acc0, acc2, acc1, 1)
        BODY(i+4, 0, LA, LB, acc1, acc0, acc2, 1)
        BODY(i+5, 1, LB, LA, acc2, acc1, acc0, 1)
    }
#undef BODY
}

extern "C" void kernel_launch(void* const* d_in, const int* in_sizes, int n_in,
                              void* d_out, int out_size, void* d_ws, size_t ws_size,
                              hipStream_t stream) {
    const float* inp = (const float*)d_in[0];
    const float* wgt = (const float*)d_in[1];
    const float* bia = (const float*)d_in[2];
    float* out = (float*)d_out;
    prep_bfrag<<<dim3((NLVL*3*5*64 + 255)/256), dim3(256), 0, stream>>>(wgt);
    conv_kernel<<<dim3(NBLOCK), dim3(256), 0, stream>>>(inp, bia, out);
}